// Round 12
// baseline (110.078 us; speedup 1.0000x reference)
//
#include <hip/hip_runtime.h>
#include <stdint.h>

// out[b,c] = <x_b/||x_b||, a_c/||a_c||>, B=16384, C=2048, D=1024, fp32 in/out.
// Pass 1: fp32 row-normalize -> bf16 into d_ws (single merged launch).
// Pass 2: bf16 MFMA GEMM. R12: OCCUPANCY route (m97/m114 mechanism).
//   128x128 tile, 4 waves (64x64/wave), BK=32, dbuf LDS = 32 KiB,
//   ~120 unified regs (__launch_bounds__(256,4)) -> 4 blocks/CU.
//   Per tile: stage(t+1) -> read 8 frags -> 16 independent MFMA -> vmcnt(0)
//   -> barrier. Stalls/epilogue covered by 3 co-resident blocks (TLP), not
//   by intra-block scheduling. Swizzle: [row][32] bf16 rows of 4x16B slots,
//   stored slot = slot ^ ((row>>2)&3) -> 2 lanes/bank-group (free, m136);
//   source pre-swizzled, gload_lds dest linear (rule #21).
//   Grid 2048 = 8 full rounds, XCD-chunked swizzle (2048%8==0).

#define D_DIM 1024
#define N_DIM 2048
#define BMt 128
#define BNt 128
#define BKt 32
#define NKT 32      // D_DIM / BKt

typedef __bf16 bf16x8 __attribute__((ext_vector_type(8)));
typedef float  f32x4  __attribute__((ext_vector_type(4)));

__device__ __forceinline__ unsigned short f2bf(float f) {
    union { float f; uint32_t u; } v; v.f = f;
    uint32_t r = v.u + 0x7fffu + ((v.u >> 16) & 1u);  // RNE
    return (unsigned short)(r >> 16);
}

// One block per row (X rows then A rows): 256 threads x float4 = 1024 floats.
__global__ __launch_bounds__(256) void normalize_rows(
        const float* __restrict__ x, const float* __restrict__ a,
        unsigned short* __restrict__ xn, unsigned short* __restrict__ an,
        int Bn) {
    const int blk = blockIdx.x;
    const float* in = (blk < Bn) ? x : a;
    unsigned short* out = (blk < Bn) ? xn : an;
    const int row = (blk < Bn) ? blk : blk - Bn;
    const int t = threadIdx.x;
    const float4 v = ((const float4*)(in + (size_t)row * D_DIM))[t];
    float ss = v.x * v.x + v.y * v.y + v.z * v.z + v.w * v.w;
#pragma unroll
    for (int o = 1; o < 64; o <<= 1) ss += __shfl_xor(ss, o);
    __shared__ float red[4];
    if ((t & 63) == 0) red[t >> 6] = ss;
    __syncthreads();
    const float tot = red[0] + red[1] + red[2] + red[3];
    const float scale = 1.0f / fmaxf(sqrtf(tot), 1e-8f);
    ushort4 o;
    o.x = f2bf(v.x * scale);
    o.y = f2bf(v.y * scale);
    o.z = f2bf(v.z * scale);
    o.w = f2bf(v.w * scale);
    ((ushort4*)(out + (size_t)row * D_DIM))[t] = o;
}

__device__ __forceinline__ void gload_lds16(const void* g, void* l) {
    __builtin_amdgcn_global_load_lds(
        (const __attribute__((address_space(1))) void*)g,
        (__attribute__((address_space(3))) void*)l,
        16, 0, 0);
}

#define BAR()     asm volatile("s_barrier" ::: "memory")
#define VMCNT0()  asm volatile("s_waitcnt vmcnt(0)" ::: "memory")

// One K-tile, buffer parity P. LAST: no stage, no end sync.
template<int P, bool LAST>
__device__ __forceinline__ void ktile(
        int t,
        const unsigned short* __restrict__ sA,  // A + (rowA0+grow)*D + gswz
        const unsigned short* __restrict__ sB,
        char* lds0, int dstT,                   // tid*16
        const char* aB0, const char* aB1,       // per-lane frag bases, parity 0/1
        const char* bB0, const char* bB1,
        f32x4 (&acc)[4][4])
{
    // stage A(t+1), B(t+1) into parity P^1 (disjoint from this tile's reads)
    if constexpr (!LAST) {
        const int k1 = (t + 1) * BKt;
#pragma unroll
        for (int j = 0; j < 2; ++j) {
            gload_lds16(sA + (size_t)(j * 64) * D_DIM + k1,
                        lds0 + (P ^ 1) * 16384 + j * 4096 + dstT);
            gload_lds16(sB + (size_t)(j * 64) * D_DIM + k1,
                        lds0 + (P ^ 1) * 16384 + 8192 + j * 4096 + dstT);
        }
    }

    // fragment reads for tile t (parity P): 4 A + 4 B ds_read_b128
    const char* aB = P ? aB1 : aB0;
    const char* bB = P ? bB1 : bB0;
    bf16x8 af[4], bf[4];
#pragma unroll
    for (int m = 0; m < 4; ++m) af[m] = *(const bf16x8*)(aB + m * 1024);
#pragma unroll
    for (int n = 0; n < 4; ++n) bf[n] = *(const bf16x8*)(bB + n * 1024);

    // 16 independent MFMA (one per acc cell; compiler inserts lgkm waits)
#pragma unroll
    for (int m = 0; m < 4; ++m)
#pragma unroll
        for (int n = 0; n < 4; ++n)
            acc[m][n] = __builtin_amdgcn_mfma_f32_16x16x32_bf16(
                af[m], bf[n], acc[m][n], 0, 0, 0);

    if constexpr (!LAST) {
        VMCNT0();   // my stage(t+1) landed (issued ~1 tile ago)
        BAR();      // all waves' stage landed -> next tile may read (race rule)
    }
}

__global__ __launch_bounds__(256, 4) void gemm128(
        const unsigned short* __restrict__ A,
        const unsigned short* __restrict__ Bm,
        float* __restrict__ Cg)
{
    __shared__ unsigned short lds[16384];  // 32 KiB: 2 bufs x (A 8KB + B 8KB)
    char* lds0 = (char*)lds;

    // XCD-chunked swizzle: 2048 wgs, 256 per XCD (contiguous bm span)
    const int nwg = gridDim.x;          // 2048
    const int cpx = nwg >> 3;           // 256
    const int wg  = ((int)blockIdx.x & 7) * cpx + ((int)blockIdx.x >> 3);
    const int bm  = wg >> 4;            // 0..127
    const int bn  = wg & 15;            // 0..15
    const int rowA0 = bm * BMt;
    const int rowB0 = bn * BNt;

    const int tid  = threadIdx.x;
    const int lane = tid & 63;
    const int wid  = tid >> 6;          // 0..3
    const int wr   = wid >> 1;          // 0..1 -> 64-row half
    const int wc   = wid & 1;           // 0..1 -> 64-col half
    const int rl = lane & 15, ts = lane >> 4;
    const int r2 = (rl >> 2) & 3;

    // per-lane frag base pointers: addr = (row)*64 + ((ts^r2)<<4); row = w*64+f*16+rl
    const int swz = ((ts ^ r2) << 4);
    const char* aB0 = lds0 + (wr * 64 + rl) * 64 + swz;
    const char* aB1 = aB0 + 16384;
    const char* bB0 = lds0 + 8192 + (wc * 64 + rl) * 64 + swz;
    const char* bB1 = bB0 + 16384;

    // staging: thread -> (row = j*64 + (tid>>2), slot = tid&3), dest linear
    // global col pre-swizzled: ((tid&3) ^ ((tid>>4)&3)) * 8 elems
    const int gswz = (((tid & 3) ^ ((tid >> 4) & 3)) << 3);
    const unsigned short* sA = A  + (size_t)(rowA0 + (tid >> 2)) * D_DIM + gswz;
    const unsigned short* sB = Bm + (size_t)(rowB0 + (tid >> 2)) * D_DIM + gswz;
    const int dstT = tid * 16;

    f32x4 acc[4][4] = {};

    // prologue: stage tile 0 into parity 0; vmcnt(0) -> barrier
#pragma unroll
    for (int j = 0; j < 2; ++j) {
        gload_lds16(sA + (size_t)(j * 64) * D_DIM, lds0 + j * 4096 + dstT);
        gload_lds16(sB + (size_t)(j * 64) * D_DIM, lds0 + 8192 + j * 4096 + dstT);
    }
    VMCNT0();
    BAR();

#pragma unroll 1
    for (int t = 0; t < NKT - 2; t += 2) {
        ktile<0, false>(t,     sA, sB, lds0, dstT, aB0, aB1, bB0, bB1, acc);
        ktile<1, false>(t + 1, sA, sB, lds0, dstT, aB0, aB1, bB0, bB1, acc);
    }
    ktile<0, false>(NKT - 2, sA, sB, lds0, dstT, aB0, aB1, bB0, bB1, acc);
    ktile<1, true >(NKT - 1, sA, sB, lds0, dstT, aB0, aB1, bB0, bB1, acc);

    // epilogue: C/D layout col=lane&15, row=(lane>>4)*4+j (m89-verified)
    const int crow0 = rowA0 + wr * 64 + ts * 4;
    const int ccol0 = rowB0 + wc * 64 + rl;
#pragma unroll
    for (int m = 0; m < 4; ++m)
#pragma unroll
        for (int n = 0; n < 4; ++n)
#pragma unroll
            for (int j = 0; j < 4; ++j)
                Cg[(size_t)(crow0 + m * 16 + j) * N_DIM + ccol0 + n * 16] = acc[m][n][j];
}

extern "C" void kernel_launch(void* const* d_in, const int* in_sizes, int n_in,
                              void* d_out, int out_size, void* d_ws, size_t ws_size,
                              hipStream_t stream) {
    const float* x = (const float*)d_in[0];   // [B, D]
    const float* a = (const float*)d_in[1];   // [C, D]
    float* out = (float*)d_out;               // [B, C]

    const int Bn = in_sizes[0] / D_DIM;  // 16384
    const int Cn = in_sizes[1] / D_DIM;  // 2048

    unsigned short* xn = (unsigned short*)d_ws;            // [B][D] bf16
    unsigned short* an = xn + (size_t)Bn * D_DIM;          // [C][D] bf16

    normalize_rows<<<Bn + Cn, 256, 0, stream>>>(x, a, xn, an, Bn);

    const int grid = (Bn / BMt) * (Cn / BNt);  // 128 * 16 = 2048
    gemm128<<<grid, 256, 0, stream>>>(xn, an, out);
}

// Round 13
// 98.228 us; speedup vs baseline: 1.1206x; 1.1206x over previous
//
#include <hip/hip_runtime.h>
#include <stdint.h>

// out[b,c] = <x_b/||x_b||, a_c/||a_c||>, B=16384, C=2048, D=1024, fp32 in/out.
// Pass 1: fp32 row-normalize -> bf16 into d_ws (single merged launch).
// Pass 2: bf16 MFMA GEMM. R13: 2 blocks/CU TLP with the PROVEN-0-conflict
//   geometry. 128x128 tile, 4 waves (2x2 of 64x64), BK=64, dbuf LDS=64 KiB
//   (2 bufs x (A 16KB + B 16KB)). __launch_bounds__(256,2) -> 2 blocks/CU:
//   one block's vmcnt/barrier drains and C-write epilogue overlap the other
//   block's MFMA loop (m114 TLP), which R6's 128-KiB design could not do.
//   LDS rows are 128 B ([row][64] bf16), row&7 XOR swizzle (R6-proven, 0
//   conflicts); source pre-swizzled, gload_lds dest linear (rule #21).
//   Per K-tile: stage(t+1) 8 DMA -> 16 ds_read_b128 (precomputed swizzled
//   base ptrs, R10) -> 32 MFMA -> vmcnt(0) -> barrier. Stage issued ~1240cyc
//   before its wait (HBM ~900). Grid 2048, XCD-chunked (2048%8==0).

#define D_DIM 1024
#define N_DIM 2048
#define BMt 128
#define BNt 128
#define BKt 64
#define NKT 16      // D_DIM / BKt

typedef __bf16 bf16x8 __attribute__((ext_vector_type(8)));
typedef float  f32x4  __attribute__((ext_vector_type(4)));

__device__ __forceinline__ unsigned short f2bf(float f) {
    union { float f; uint32_t u; } v; v.f = f;
    uint32_t r = v.u + 0x7fffu + ((v.u >> 16) & 1u);  // RNE
    return (unsigned short)(r >> 16);
}

// One block per row (X rows then A rows): 256 threads x float4 = 1024 floats.
__global__ __launch_bounds__(256) void normalize_rows(
        const float* __restrict__ x, const float* __restrict__ a,
        unsigned short* __restrict__ xn, unsigned short* __restrict__ an,
        int Bn) {
    const int blk = blockIdx.x;
    const float* in = (blk < Bn) ? x : a;
    unsigned short* out = (blk < Bn) ? xn : an;
    const int row = (blk < Bn) ? blk : blk - Bn;
    const int t = threadIdx.x;
    const float4 v = ((const float4*)(in + (size_t)row * D_DIM))[t];
    float ss = v.x * v.x + v.y * v.y + v.z * v.z + v.w * v.w;
#pragma unroll
    for (int o = 1; o < 64; o <<= 1) ss += __shfl_xor(ss, o);
    __shared__ float red[4];
    if ((t & 63) == 0) red[t >> 6] = ss;
    __syncthreads();
    const float tot = red[0] + red[1] + red[2] + red[3];
    const float scale = 1.0f / fmaxf(sqrtf(tot), 1e-8f);
    ushort4 o;
    o.x = f2bf(v.x * scale);
    o.y = f2bf(v.y * scale);
    o.z = f2bf(v.z * scale);
    o.w = f2bf(v.w * scale);
    ((ushort4*)(out + (size_t)row * D_DIM))[t] = o;
}

__device__ __forceinline__ void gload_lds16(const void* g, void* l) {
    __builtin_amdgcn_global_load_lds(
        (const __attribute__((address_space(1))) void*)g,
        (__attribute__((address_space(3))) void*)l,
        16, 0, 0);
}

#define BAR()     asm volatile("s_barrier" ::: "memory")
#define VMCNT0()  asm volatile("s_waitcnt vmcnt(0)" ::: "memory")

// One K-tile, buffer parity P. LAST: no stage, no end sync.
// LDS regions (64 KiB): parity p: A at p*32768, B at p*32768 + 16384 (bytes).
template<int P, bool LAST>
__device__ __forceinline__ void ktile(
        int t,
        const unsigned short* __restrict__ sA,  // A + (rowA0+grow)*D + gswz
        const unsigned short* __restrict__ sB,
        char* lds0, int dstT,                   // tid*16
        const char* const (&pA)[2][2], const char* const (&pB)[2][2],
        f32x4 (&acc)[4][4])
{
    // stage A(t+1), B(t+1) into parity P^1 (region's readers drained at t-1 bar)
    if constexpr (!LAST) {
        const int k1 = (t + 1) * BKt;
#pragma unroll
        for (int j = 0; j < 4; ++j) {
            gload_lds16(sA + (size_t)(j * 32) * D_DIM + k1,
                        lds0 + (P ^ 1) * 32768 + j * 4096 + dstT);
            gload_lds16(sB + (size_t)(j * 32) * D_DIM + k1,
                        lds0 + (P ^ 1) * 32768 + 16384 + j * 4096 + dstT);
        }
    }

    // fragment reads for tile t (parity P): 8 A + 8 B ds_read_b128, 0-conflict
    bf16x8 af[4][2], bf[4][2];
#pragma unroll
    for (int m = 0; m < 4; ++m)
#pragma unroll
        for (int kk = 0; kk < 2; ++kk)
            af[m][kk] = *(const bf16x8*)(pA[P][kk] + m * 2048);
#pragma unroll
    for (int n = 0; n < 4; ++n)
#pragma unroll
        for (int kk = 0; kk < 2; ++kk)
            bf[n][kk] = *(const bf16x8*)(pB[P][kk] + n * 2048);

    // 32 MFMA (compiler inserts lgkm waits for the frag deps)
#pragma unroll
    for (int m = 0; m < 4; ++m)
#pragma unroll
        for (int n = 0; n < 4; ++n)
#pragma unroll
            for (int kk = 0; kk < 2; ++kk)
                acc[m][n] = __builtin_amdgcn_mfma_f32_16x16x32_bf16(
                    af[m][kk], bf[n][kk], acc[m][n], 0, 0, 0);

    if constexpr (!LAST) {
        VMCNT0();   // my stage(t+1) landed (issued ~1240 cyc ago)
        BAR();      // all waves' stage landed -> next tile may read (race rule)
    }
}

__global__ __launch_bounds__(256, 2) void gemm128(
        const unsigned short* __restrict__ A,
        const unsigned short* __restrict__ Bm,
        float* __restrict__ Cg)
{
    __shared__ unsigned short lds[32768];  // 64 KiB
    char* lds0 = (char*)lds;

    // XCD-chunked swizzle: 2048 wgs, 256 per XCD (contiguous bm span)
    const int nwg = gridDim.x;          // 2048
    const int cpx = nwg >> 3;           // 256
    const int wg  = ((int)blockIdx.x & 7) * cpx + ((int)blockIdx.x >> 3);
    const int bm  = wg >> 4;            // 0..127
    const int bn  = wg & 15;            // 0..15
    const int rowA0 = bm * BMt;
    const int rowB0 = bn * BNt;

    const int tid  = threadIdx.x;
    const int lane = tid & 63;
    const int wid  = tid >> 6;          // 0..3
    const int wr   = wid >> 1;          // 0..1 -> 64-row half
    const int wc   = wid & 1;           // 0..1 -> 64-col half
    const int rl = lane & 15, ts = lane >> 4, r7 = rl & 7;

    // precomputed per-lane frag base ptrs (R10 identities: row&7 == rl&7;
    // kk=1 slot = 4^(ts^r7)):
    const int swz0 = ((ts ^ r7) << 4);
    const int swz1 = (((4 + ts) ^ r7) << 4);
    const int aRow = (wr * 64 + rl) * 128;
    const int bRow = (wc * 64 + rl) * 128;
    const char* pA[2][2];
    const char* pB[2][2];
#pragma unroll
    for (int p = 0; p < 2; ++p) {
        pA[p][0] = lds0 + p * 32768 + aRow + swz0;
        pA[p][1] = lds0 + p * 32768 + aRow + swz1;
        pB[p][0] = lds0 + p * 32768 + 16384 + bRow + swz0;
        pB[p][1] = lds0 + p * 32768 + 16384 + bRow + swz1;
    }

    // staging: thread -> row = j*32 + (tid>>3), col-slot = tid&7 (16B each);
    // linear dest byte = j*4096 + tid*16; source col pre-swizzled (rule #21).
    const int gswz = (((tid & 7) ^ ((tid >> 3) & 7)) << 3);
    const unsigned short* sA = A  + (size_t)(rowA0 + (tid >> 3)) * D_DIM + gswz;
    const unsigned short* sB = Bm + (size_t)(rowB0 + (tid >> 3)) * D_DIM + gswz;
    const int dstT = tid * 16;

    f32x4 acc[4][4] = {};

    // prologue: stage tile 0 into parity 0; vmcnt(0) -> barrier
#pragma unroll
    for (int j = 0; j < 4; ++j) {
        gload_lds16(sA + (size_t)(j * 32) * D_DIM, lds0 + j * 4096 + dstT);
        gload_lds16(sB + (size_t)(j * 32) * D_DIM, lds0 + 16384 + j * 4096 + dstT);
    }
    VMCNT0();
    BAR();

#pragma unroll 1
    for (int t = 0; t < NKT - 2; t += 2) {
        ktile<0, false>(t,     sA, sB, lds0, dstT, pA, pB, acc);
        ktile<1, false>(t + 1, sA, sB, lds0, dstT, pA, pB, acc);
    }
    ktile<0, false>(NKT - 2, sA, sB, lds0, dstT, pA, pB, acc);
    ktile<1, true >(NKT - 1, sA, sB, lds0, dstT, pA, pB, acc);

    // epilogue: C/D layout col=lane&15, row=(lane>>4)*4+j (m89-verified)
    const int crow0 = rowA0 + wr * 64 + ts * 4;
    const int ccol0 = rowB0 + wc * 64 + rl;
#pragma unroll
    for (int m = 0; m < 4; ++m)
#pragma unroll
        for (int n = 0; n < 4; ++n)
#pragma unroll
            for (int j = 0; j < 4; ++j)
                Cg[(size_t)(crow0 + m * 16 + j) * N_DIM + ccol0 + n * 16] = acc[m][n][j];
}

extern "C" void kernel_launch(void* const* d_in, const int* in_sizes, int n_in,
                              void* d_out, int out_size, void* d_ws, size_t ws_size,
                              hipStream_t stream) {
    const float* x = (const float*)d_in[0];   // [B, D]
    const float* a = (const float*)d_in[1];   // [C, D]
    float* out = (float*)d_out;               // [B, C]

    const int Bn = in_sizes[0] / D_DIM;  // 16384
    const int Cn = in_sizes[1] / D_DIM;  // 2048

    unsigned short* xn = (unsigned short*)d_ws;            // [B][D] bf16
    unsigned short* an = xn + (size_t)Bn * D_DIM;          // [C][D] bf16

    normalize_rows<<<Bn + Cn, 256, 0, stream>>>(x, a, xn, an, Bn);

    const int grid = (Bn / BMt) * (Cn / BNt);  // 128 * 16 = 2048
    gemm128<<<grid, 256, 0, stream>>>(xn, an, out);
}

// Round 14
// 93.136 us; speedup vs baseline: 1.1819x; 1.0547x over previous
//
#include <hip/hip_runtime.h>
#include <stdint.h>

// out[b,c] = <x_b/||x_b||, a_c/||a_c||>, B=16384, C=2048, D=1024, fp32 in/out.
// Pass 1: fp32 row-normalize -> bf16 into d_ws (single merged launch).
// Pass 2: bf16 MFMA GEMM. R14: single-barrier free-run tile at 256x256.
//   Mechanism (from R13 vs R3-R10 data): MFMA issue backpressure blocks a
//   wave's subsequent ds_read issue; per-phase barriers re-sync all waves so
//   LDS and MFMA pipes strictly alternate (observed 5655 cyc/tile = exact
//   serial sum). Removing intra-tile barriers lets the 8 waves drift within
//   the tile window so one wave's reads run under another's MFMAs (m114).
//   Per K-tile: 8 stage DMAs (issued first, >=2500cyc before their wait)
//   -> 24 conflict-free ds_read_b128 (precomputed swizzled base ptrs)
//   -> 64 MFMA (compiler emits fine-grained lgkmcnt) -> vmcnt(0) -> barrier.
//   Race rule: each wave's ds_reads complete before its barrier arrival
//   (compiler lgkm waits precede the MFMAs that precede the barrier), and
//   boundary is vmcnt -> barrier -> read. Staging targets parity P^1 only,
//   read-parity P regions are never written during the tile.
//   LDS rows 128 B, row&7 XOR swizzle (0 conflicts, R6-proven); source
//   pre-swizzled, gload_lds dest linear (rule #21). XCD-chunked grid.

#define D_DIM 1024
#define N_DIM 2048
#define BMt 256
#define BNt 256
#define BKt 64
#define NKT 16      // D_DIM / BKt

typedef __bf16 bf16x8 __attribute__((ext_vector_type(8)));
typedef float  f32x4  __attribute__((ext_vector_type(4)));

__device__ __forceinline__ unsigned short f2bf(float f) {
    union { float f; uint32_t u; } v; v.f = f;
    uint32_t r = v.u + 0x7fffu + ((v.u >> 16) & 1u);  // RNE
    return (unsigned short)(r >> 16);
}

// One block per row (X rows then A rows): 256 threads x float4 = 1024 floats.
__global__ __launch_bounds__(256) void normalize_rows(
        const float* __restrict__ x, const float* __restrict__ a,
        unsigned short* __restrict__ xn, unsigned short* __restrict__ an,
        int Bn) {
    const int blk = blockIdx.x;
    const float* in = (blk < Bn) ? x : a;
    unsigned short* out = (blk < Bn) ? xn : an;
    const int row = (blk < Bn) ? blk : blk - Bn;
    const int t = threadIdx.x;
    const float4 v = ((const float4*)(in + (size_t)row * D_DIM))[t];
    float ss = v.x * v.x + v.y * v.y + v.z * v.z + v.w * v.w;
#pragma unroll
    for (int o = 1; o < 64; o <<= 1) ss += __shfl_xor(ss, o);
    __shared__ float red[4];
    if ((t & 63) == 0) red[t >> 6] = ss;
    __syncthreads();
    const float tot = red[0] + red[1] + red[2] + red[3];
    const float scale = 1.0f / fmaxf(sqrtf(tot), 1e-8f);
    ushort4 o;
    o.x = f2bf(v.x * scale);
    o.y = f2bf(v.y * scale);
    o.z = f2bf(v.z * scale);
    o.w = f2bf(v.w * scale);
    ((ushort4*)(out + (size_t)row * D_DIM))[t] = o;
}

__device__ __forceinline__ void gload_lds16(const void* g, void* l) {
    __builtin_amdgcn_global_load_lds(
        (const __attribute__((address_space(1))) void*)g,
        (__attribute__((address_space(3))) void*)l,
        16, 0, 0);
}

#define BAR()     asm volatile("s_barrier" ::: "memory")
#define VMCNT0()  asm volatile("s_waitcnt vmcnt(0)" ::: "memory")

// LDS byte regions (128 KiB): A[p] at p*65536 (32 KB, rows 0-255 linear),
// B[p] at 32768 + p*65536.
template<int P, bool STAGE>
__device__ __forceinline__ void ktile(
        int t,
        const unsigned short* __restrict__ sA,   // A + rowA0*D + voff (per-lane)
        const unsigned short* __restrict__ sB,
        char* lds0, int dstW,                    // wid*1024 (byte)
        const char* const (&pA)[2][2], const char* const (&pB)[2][2],
        f32x4 (&acc)[8][4])
{
    // ---- stage all 8 half-tile DMAs for t+1 FIRST (earliest issue) ----
    if constexpr (STAGE) {
        const int k1 = (t + 1) * BKt;
#pragma unroll
        for (int j = 0; j < 2; ++j) {
            gload_lds16(sA + (size_t)(j * 64) * D_DIM + k1,
                        lds0 + (P ^ 1) * 65536 + j * 8192 + dstW);
            gload_lds16(sA + (size_t)(128 + j * 64) * D_DIM + k1,
                        lds0 + (P ^ 1) * 65536 + 16384 + j * 8192 + dstW);
            gload_lds16(sB + (size_t)(j * 64) * D_DIM + k1,
                        lds0 + 32768 + (P ^ 1) * 65536 + j * 8192 + dstW);
            gload_lds16(sB + (size_t)(128 + j * 64) * D_DIM + k1,
                        lds0 + 32768 + (P ^ 1) * 65536 + 16384 + j * 8192 + dstW);
        }
    }

    // ---- 24 fragment reads for tile t (parity P), conflict-free ----
    bf16x8 af[8][2], bf[4][2];
#pragma unroll
    for (int m = 0; m < 8; ++m)
#pragma unroll
        for (int kk = 0; kk < 2; ++kk)
            af[m][kk] = *(const bf16x8*)(pA[P][kk] + m * 2048);
#pragma unroll
    for (int n = 0; n < 4; ++n)
#pragma unroll
        for (int kk = 0; kk < 2; ++kk)
            bf[n][kk] = *(const bf16x8*)(pB[P][kk] + n * 2048);

    // ---- 64 MFMA (compiler inserts fine-grained lgkmcnt before uses) ----
    __builtin_amdgcn_s_setprio(1);
#pragma unroll
    for (int m = 0; m < 8; ++m)
#pragma unroll
        for (int n = 0; n < 4; ++n)
#pragma unroll
            for (int kk = 0; kk < 2; ++kk)
                acc[m][n] = __builtin_amdgcn_mfma_f32_16x16x32_bf16(
                    af[m][kk], bf[n][kk], acc[m][n], 0, 0, 0);
    __builtin_amdgcn_s_setprio(0);

    // ---- boundary: my DMAs landed -> all waves' landed -> next tile reads
    if constexpr (STAGE) {
        VMCNT0();
        BAR();
    }
}

__global__ __launch_bounds__(512, 2) void gemm256(
        const unsigned short* __restrict__ A,
        const unsigned short* __restrict__ Bm,
        float* __restrict__ Cg)
{
    __shared__ unsigned short lds[65536];  // 128 KiB
    char* lds0 = (char*)lds;

    const int nwg = gridDim.x;          // 512
    const int cpx = nwg >> 3;           // 64
    const int wg  = ((int)blockIdx.x & 7) * cpx + ((int)blockIdx.x >> 3);
    const int bm  = wg >> 3;            // 0..63
    const int bn  = wg & 7;             // 0..7
    const int rowA0 = bm * BMt;
    const int rowB0 = bn * BNt;

    const int tid  = threadIdx.x;
    const int lane = tid & 63;
    const int wid  = tid >> 6;          // 0..7
    const int wr   = wid >> 2;          // 0..1 -> 128-row half
    const int wc   = wid & 3;           // 0..3 -> 64-col slice
    const int rl = lane & 15, ts = lane >> 4, r7 = rl & 7;

    // precomputed per-lane frag base ptrs (R10 identities: row&7 == rl&7;
    // kk=1 slot = 4^(ts^r7)):
    const int swz0 = ((ts ^ r7) << 4);
    const int swz1 = (((4 + ts) ^ r7) << 4);
    const int aRow = (wr * 128 + rl) * 128;
    const int bRow = (wc * 64 + rl) * 128;
    const char* pA[2][2];
    const char* pB[2][2];
#pragma unroll
    for (int p = 0; p < 2; ++p) {
        pA[p][0] = lds0 + p * 65536 + aRow + swz0;
        pA[p][1] = lds0 + p * 65536 + aRow + swz1;
        pB[p][0] = lds0 + 32768 + p * 65536 + bRow + swz0;
        pB[p][1] = lds0 + 32768 + p * 65536 + bRow + swz1;
    }

    // staging bases: per-lane voff folded into src ptrs (source pre-swizzled)
    const int gcol = (((tid & 7) ^ ((tid >> 3) & 7)) << 3);
    const int grow = (tid >> 3);
    const int voff = grow * D_DIM + gcol;
    const unsigned short* sA = A  + (size_t)rowA0 * D_DIM + voff;
    const unsigned short* sB = Bm + (size_t)rowB0 * D_DIM + voff;
    const int dstW = wid * 1024;

    f32x4 acc[8][4] = {};

    // prologue: stage tile 0 (parity 0); vmcnt(0) -> barrier
#pragma unroll
    for (int j = 0; j < 2; ++j) {
        gload_lds16(sA + (size_t)(j * 64) * D_DIM,        lds0 + j * 8192 + dstW);
        gload_lds16(sA + (size_t)(128 + j * 64) * D_DIM,  lds0 + 16384 + j * 8192 + dstW);
        gload_lds16(sB + (size_t)(j * 64) * D_DIM,        lds0 + 32768 + j * 8192 + dstW);
        gload_lds16(sB + (size_t)(128 + j * 64) * D_DIM,  lds0 + 32768 + 16384 + j * 8192 + dstW);
    }
    VMCNT0();
    BAR();

#pragma unroll 1
    for (int t = 0; t < NKT - 2; t += 2) {
        ktile<0, true>(t,     sA, sB, lds0, dstW, pA, pB, acc);
        ktile<1, true>(t + 1, sA, sB, lds0, dstW, pA, pB, acc);
    }
    ktile<0, true >(NKT - 2, sA, sB, lds0, dstW, pA, pB, acc);
    ktile<1, false>(NKT - 1, sA, sB, lds0, dstW, pA, pB, acc);

    // epilogue: C/D layout col=lane&15, row=(lane>>4)*4+j (m89-verified)
    const int crow0 = rowA0 + wr * 128 + ts * 4;
    const int ccol0 = rowB0 + wc * 64 + rl;
#pragma unroll
    for (int m = 0; m < 8; ++m)
#pragma unroll
        for (int n = 0; n < 4; ++n)
#pragma unroll
            for (int j = 0; j < 4; ++j)
                Cg[(size_t)(crow0 + m * 16 + j) * N_DIM + ccol0 + n * 16] = acc[m][n][j];
}

extern "C" void kernel_launch(void* const* d_in, const int* in_sizes, int n_in,
                              void* d_out, int out_size, void* d_ws, size_t ws_size,
                              hipStream_t stream) {
    const float* x = (const float*)d_in[0];   // [B, D]
    const float* a = (const float*)d_in[1];   // [C, D]
    float* out = (float*)d_out;               // [B, C]

    const int Bn = in_sizes[0] / D_DIM;  // 16384
    const int Cn = in_sizes[1] / D_DIM;  // 2048

    unsigned short* xn = (unsigned short*)d_ws;            // [B][D] bf16
    unsigned short* an = xn + (size_t)Bn * D_DIM;          // [C][D] bf16

    normalize_rows<<<Bn + Cn, 256, 0, stream>>>(x, a, xn, an, Bn);

    const int grid = (Bn / BMt) * (Cn / BNt);  // 64 * 8 = 512
    gemm256<<<grid, 512, 0, stream>>>(xn, an, out);
}